// Round 4
// baseline (529.839 us; speedup 1.0000x reference)
//
#include <hip/hip_runtime.h>
#include <hip/hip_bf16.h>

#define LEAKY_ATT 0.2f
#define LEAKY_ACT 0.01f
#define BSHIFT 8
#define CH 4096

__device__ __forceinline__ float leaky(float x, float s) { return x >= 0.f ? x : s * x; }

__device__ __forceinline__ uint f2bf(float f) {
  __hip_bfloat16 h = __float2bfloat16(f);  // RTNE
  return (uint)*reinterpret_cast<ushort*>(&h);
}

__device__ __forceinline__ float bf_lo(uint q) { return __uint_as_float(q << 16); }
__device__ __forceinline__ float bf_hi(uint q) { return __uint_as_float(q & 0xffff0000u); }

// ============================ CSR build: two-level counting sort ============================
__global__ __launch_bounds__(256) void k_bhist(const int* __restrict__ dst, int e, int nb,
                                               int* __restrict__ bcnt) {
  __shared__ int cnt[512];
  for (int i = threadIdx.x; i < 512; i += 256) cnt[i] = 0;
  __syncthreads();
  for (int i = blockIdx.x * 256 + threadIdx.x; i < e; i += gridDim.x * 256)
    atomicAdd(&cnt[dst[i] >> BSHIFT], 1);
  __syncthreads();
  for (int i = threadIdx.x; i < nb; i += 256)
    if (cnt[i]) atomicAdd(&bcnt[i], cnt[i]);
}

__global__ __launch_bounds__(512) void k_bscan(const int* __restrict__ bcnt, int nb,
                                               int* __restrict__ bbase, int* __restrict__ bcur) {
  __shared__ int sh[512];
  int t = threadIdx.x;
  int orig = (t < nb) ? bcnt[t] : 0;
  sh[t] = orig;
  __syncthreads();
  for (int off = 1; off < 512; off <<= 1) {
    int v = (t >= off) ? sh[t - off] : 0;
    __syncthreads();
    sh[t] += v;
    __syncthreads();
  }
  if (t < nb) {
    int ex = sh[t] - orig;
    bbase[t] = ex;
    bcur[t] = ex;
    if (t == nb - 1) bbase[nb] = sh[t];
  }
}

__global__ __launch_bounds__(256) void k_bucket(const int* __restrict__ src,
                                                const int* __restrict__ dst, int e, int nb,
                                                int* __restrict__ bcur, uint* __restrict__ bpair) {
  __shared__ uint spair[CH];
  __shared__ ushort skey[CH];
  __shared__ ushort srank[CH];
  __shared__ int cnt[512];
  __shared__ int gb[512];
  int t = threadIdx.x;
  int c0 = blockIdx.x * CH;
  int cn = min(CH, e - c0);
  if (cn <= 0) return;
  for (int i = t; i < 512; i += 256) cnt[i] = 0;
  __syncthreads();
  for (int i = t; i < cn; i += 256) {
    int s = src[c0 + i];
    int d = dst[c0 + i];
    int k = d >> BSHIFT;
    spair[i] = ((uint)(d & ((1 << BSHIFT) - 1)) << 20) | (uint)s;
    skey[i] = (ushort)k;
    srank[i] = (ushort)atomicAdd(&cnt[k], 1);
  }
  __syncthreads();
  for (int k = t; k < nb; k += 256)
    gb[k] = cnt[k] ? atomicAdd(&bcur[k], cnt[k]) : 0;
  __syncthreads();
  for (int i = t; i < cn; i += 256) {
    bpair[gb[skey[i]] + srank[i]] = spair[i];
  }
}

__global__ __launch_bounds__(256) void k_csr(const uint* __restrict__ bpair,
                                             const int* __restrict__ bbase, int n,
                                             int* __restrict__ rowptr, int* __restrict__ col) {
  __shared__ int deg[256];
  __shared__ int cur[256];
  int b = blockIdx.x, t = threadIdx.x;
  int e0 = bbase[b], e1 = bbase[b + 1];
  deg[t] = 0;
  __syncthreads();
  for (int i = e0 + t; i < e1; i += 256)
    atomicAdd(&deg[bpair[i] >> 20], 1);
  __syncthreads();
  int v = deg[t];
  cur[t] = v;
  __syncthreads();
  for (int off = 1; off < 256; off <<= 1) {
    int u = (t >= off) ? cur[t - off] : 0;
    __syncthreads();
    cur[t] += u;
    __syncthreads();
  }
  int incl = cur[t];
  int gnode = b * 256 + t;
  if (gnode < n) rowptr[gnode + 1] = e0 + incl;
  if (b == 0 && t == 0) rowptr[0] = 0;
  __syncthreads();
  cur[t] = e0 + incl - v;
  __syncthreads();
  for (int i = e0 + t; i < e1; i += 256) {
    uint pk = bpair[i];
    int loc = pk >> 20;
    int p = atomicAdd(&cur[loc], 1);
    col[p] = (int)(pk & 0xFFFFFu);
  }
}

// ============================ weight prep ============================
__global__ void k_prep_vsd(const float* __restrict__ wsrc, const float* __restrict__ wdst,
                           const float* __restrict__ asrc, const float* __restrict__ adst,
                           float* __restrict__ vsd) {
  int k = blockIdx.x;
  int i = threadIdx.x;
  float s = 0.f;
  if (i < 8) {
    for (int c = 0; c < 16; ++c) s += wsrc[k * 128 + i * 16 + c] * asrc[i * 16 + c];
  } else {
    int h = i - 8;
    for (int c = 0; c < 16; ++c) s += wdst[k * 128 + h * 16 + c] * adst[h * 16 + c];
  }
  vsd[k * 16 + i] = s;
}

__global__ void k_prep_u3(const float* __restrict__ w3s, const float* __restrict__ w3d,
                          const float* __restrict__ a3s, const float* __restrict__ a3d,
                          float* __restrict__ U) {
  int k = blockIdx.x * blockDim.x + threadIdx.x;
  if (k >= 128) return;
  U[k * 4 + 0] = w3s[k * 2 + 0];
  U[k * 4 + 1] = w3s[k * 2 + 1];
  U[k * 4 + 2] = w3s[k * 2 + 0] * a3s[0] + w3s[k * 2 + 1] * a3s[1];
  U[k * 4 + 3] = w3d[k * 2 + 0] * a3d[0] + w3d[k * 2 + 1] * a3d[1];
}

// ============================ layer 1/2 linear: XSb(bf16) = X@W, AL = X@vsd ============================
__global__ __launch_bounds__(256) void k_gemm_xs_al(const float* __restrict__ X,
                                                    const float* __restrict__ W,
                                                    const float* __restrict__ VSD,
                                                    ushort* __restrict__ XSb,
                                                    float* __restrict__ AL, int n) {
  __shared__ float xt[64][128];
  int t = threadIdx.x;
  int row0 = blockIdx.x * 64;
  for (int i = t; i < 64 * 128; i += 256) {
    int r = i >> 7, c = i & 127;
    int gr = row0 + r;
    xt[r][c] = (gr < n) ? X[gr * 128 + c] : 0.f;
  }
  __syncthreads();

  int c0 = (t & 31) * 4;
  int r0 = (t >> 5) * 8;
  float acc[8][4] = {};
  for (int k = 0; k < 128; ++k) {
    float4 wv = *reinterpret_cast<const float4*>(&W[k * 128 + c0]);
#pragma unroll
    for (int i = 0; i < 8; ++i) {
      float xv = xt[r0 + i][k];
      acc[i][0] += xv * wv.x;
      acc[i][1] += xv * wv.y;
      acc[i][2] += xv * wv.z;
      acc[i][3] += xv * wv.w;
    }
  }
#pragma unroll
  for (int i = 0; i < 8; ++i) {
    int gr = row0 + r0 + i;
    if (gr < n) {
      uint lo = f2bf(acc[i][0]) | (f2bf(acc[i][1]) << 16);
      uint hi = f2bf(acc[i][2]) | (f2bf(acc[i][3]) << 16);
      *reinterpret_cast<uint2*>(&XSb[(size_t)gr * 128 + c0]) = make_uint2(lo, hi);
    }
  }

  int node = t >> 2;
  int j0 = (t & 3) * 4;
  float a[4] = {};
  for (int k = 0; k < 128; ++k) {
    float xv = xt[node][k];
#pragma unroll
    for (int j = 0; j < 4; ++j) a[j] += xv * VSD[k * 16 + j0 + j];
  }
  int gr = row0 + node;
  if (gr < n) {
#pragma unroll
    for (int j = 0; j < 4; ++j) AL[gr * 16 + j0 + j] = a[j];
  }
}

// ============================ layer 1/2 aggregation: wave-per-node ============================
// lane covers channels {2*lane, 2*lane+1}; head h = lane>>3.
// Per 8-edge chunk: lane computes weight for (edge lane&7, head lane>>3);
// FMA loop pulls src+weight via shfl. No LDS, no barriers.
__global__ __launch_bounds__(256) void k_gat_agg(const ushort* __restrict__ XSb,
                                                 const float* __restrict__ AL,
                                                 const int* __restrict__ rowptr,
                                                 const int* __restrict__ col,
                                                 const float* __restrict__ bias,
                                                 float* __restrict__ OUT, int n, int act) {
  int t = threadIdx.x;
  int lane = t & 63;
  int node = blockIdx.x * 4 + (t >> 6);
  if (node >= n) return;
  int h = lane >> 3;   // head for weight duty AND for own channels (2*lane)>>4
  int k8 = lane & 7;   // edge slot for weight duty

  float ald = AL[(size_t)node * 16 + 8 + h];

  // self loop
  float w0 = __expf(leaky(AL[(size_t)node * 16 + h] + ald, LEAKY_ATT));
  uint qs = *reinterpret_cast<const uint*>(&XSb[(size_t)node * 128 + lane * 2]);
  float acc0 = w0 * bf_lo(qs);
  float acc1 = w0 * bf_hi(qs);
  float den = w0;

  int beg = rowptr[node], end = rowptr[node + 1];
  for (int base = beg; base < end; base += 8) {
    int cnt = end - base;  // >=1; use min(8,cnt)
    if (cnt > 8) cnt = 8;
    int cola = (k8 < cnt) ? col[base + k8] : 0;
    float wl = 0.f;
    if (k8 < cnt) {
      float lg = AL[(size_t)cola * 16 + h] + ald;
      wl = __expf(leaky(lg, LEAKY_ATT));
    }
    uint q[8];
    float wj[8];
#pragma unroll
    for (int j = 0; j < 8; ++j) {
      if (j < cnt) {
        int s = __shfl(cola, j);
        wj[j] = __shfl(wl, (lane & 0x38) | j);
        q[j] = *reinterpret_cast<const uint*>(&XSb[(size_t)s * 128 + lane * 2]);
      }
    }
#pragma unroll
    for (int j = 0; j < 8; ++j) {
      if (j < cnt) {
        float w = wj[j];
        acc0 += w * bf_lo(q[j]);
        acc1 += w * bf_hi(q[j]);
        den += w;
      }
    }
  }

  float inv = 1.f / den;
  float2 bv = *reinterpret_cast<const float2*>(&bias[lane * 2]);
  float r0 = acc0 * inv + bv.x;
  float r1 = acc1 * inv + bv.y;
  if (act) {
    r0 = leaky(r0, LEAKY_ACT);
    r1 = leaky(r1, LEAKY_ACT);
  }
  *reinterpret_cast<float2*>(&OUT[(size_t)node * 128 + lane * 2]) = make_float2(r0, r1);
}

// ============================ layer 3 ============================
__global__ __launch_bounds__(256) void k_lin3(const float* __restrict__ X,
                                              const float* __restrict__ U,
                                              float* __restrict__ XSAL3, int n) {
  __shared__ float xt[64][128];
  int t = threadIdx.x;
  int row0 = blockIdx.x * 64;
  for (int i = t; i < 64 * 128; i += 256) {
    int r = i >> 7, c = i & 127;
    int gr = row0 + r;
    xt[r][c] = (gr < n) ? X[gr * 128 + c] : 0.f;
  }
  __syncthreads();
  int node = t >> 2;
  int j = t & 3;
  float a = 0.f;
  for (int k = 0; k < 128; ++k) a += xt[node][k] * U[k * 4 + j];
  int gr = row0 + node;
  if (gr < n) XSAL3[gr * 4 + j] = a;
}

__global__ __launch_bounds__(256) void k_agg3(const float* __restrict__ XSAL3,
                                              const int* __restrict__ rowptr,
                                              const int* __restrict__ col,
                                              const float* __restrict__ b3,
                                              float* __restrict__ out, int n) {
  int node = blockIdx.x * blockDim.x + threadIdx.x;
  if (node >= n) return;
  float4 self = *reinterpret_cast<const float4*>(&XSAL3[node * 4]);
  float ald = self.w;
  float e0 = leaky(self.z + ald, LEAKY_ATT);
  float w0 = __expf(e0);
  float den = w0;
  float a0 = w0 * self.x;
  float a1 = w0 * self.y;
  int end = rowptr[node + 1];
  for (int jj = rowptr[node]; jj < end; ++jj) {
    int s = col[jj];
    float4 v = *reinterpret_cast<const float4*>(&XSAL3[s * 4]);
    float ee = leaky(v.z + ald, LEAKY_ATT);
    float w = __expf(ee);
    den += w;
    a0 += w * v.x;
    a1 += w * v.y;
  }
  out[node * 2 + 0] = a0 / den + b3[0];
  out[node * 2 + 1] = a1 / den + b3[1];
}

// ============================ launch ============================
extern "C" void kernel_launch(void* const* d_in, const int* in_sizes, int n_in,
                              void* d_out, int out_size, void* d_ws, size_t ws_size,
                              hipStream_t stream) {
  const float* x = (const float*)d_in[0];
  const int* ei = (const int*)d_in[1];
  const float* w1s = (const float*)d_in[2];
  const float* w1d = (const float*)d_in[3];
  const float* a1s = (const float*)d_in[4];
  const float* a1d = (const float*)d_in[5];
  const float* b1 = (const float*)d_in[6];
  const float* w2s = (const float*)d_in[7];
  const float* w2d = (const float*)d_in[8];
  const float* a2s = (const float*)d_in[9];
  const float* a2d = (const float*)d_in[10];
  const float* b2 = (const float*)d_in[11];
  const float* w3s = (const float*)d_in[12];
  const float* w3d = (const float*)d_in[13];
  const float* a3s = (const float*)d_in[14];
  const float* a3d = (const float*)d_in[15];
  const float* b3 = (const float*)d_in[16];

  int n = in_sizes[0] / 128;
  int e = in_sizes[1] / 2;
  const int* srcp = ei;
  const int* dstp = ei + e;

  int nb = (n + 255) >> BSHIFT;
  if (nb > 512) return;
  if (n >= (1 << 20)) return;

  size_t off = 0;
  auto alloc = [&](size_t bytes) -> void* {
    void* p = (char*)d_ws + off;
    off += (bytes + 255) & ~(size_t)255;
    return p;
  };
  int* bcnt = (int*)alloc((size_t)(nb) * 4);
  int* bbase = (int*)alloc((size_t)(nb + 1) * 4);
  int* bcur = (int*)alloc((size_t)nb * 4);
  uint* bpair = (uint*)alloc((size_t)e * 4);
  int* rowptr = (int*)alloc((size_t)(n + 1) * 4);
  int* col = (int*)alloc((size_t)e * 4);
  float* vsd1 = (float*)alloc(128 * 16 * 4);
  float* vsd2 = (float*)alloc(128 * 16 * 4);
  float* u3 = (float*)alloc(128 * 4 * 4);
  float* al = (float*)alloc((size_t)n * 16 * 4);
  ushort* xsb = (ushort*)alloc((size_t)n * 128 * 2);
  float* ha = (float*)alloc((size_t)n * 128 * 4);
  float* xsal3 = (float*)alloc((size_t)n * 4 * 4);
  if (off > ws_size) return;

  hipMemsetAsync(bcnt, 0, (size_t)nb * 4, stream);
  k_bhist<<<512, 256, 0, stream>>>(dstp, e, nb, bcnt);
  k_bscan<<<1, 512, 0, stream>>>(bcnt, nb, bbase, bcur);
  k_bucket<<<(e + CH - 1) / CH, 256, 0, stream>>>(srcp, dstp, e, nb, bcur, bpair);
  k_csr<<<nb, 256, 0, stream>>>(bpair, bbase, n, rowptr, col);

  k_prep_vsd<<<128, 16, 0, stream>>>(w1s, w1d, a1s, a1d, vsd1);
  k_prep_vsd<<<128, 16, 0, stream>>>(w2s, w2d, a2s, a2d, vsd2);
  k_prep_u3<<<1, 128, 0, stream>>>(w3s, w3d, a3s, a3d, u3);

  int gb = (n + 63) / 64;
  int ab = (n + 3) / 4;
  // layer 1
  k_gemm_xs_al<<<gb, 256, 0, stream>>>(x, w1s, vsd1, xsb, al, n);
  k_gat_agg<<<ab, 256, 0, stream>>>(xsb, al, rowptr, col, b1, ha, n, 1);
  // layer 2
  k_gemm_xs_al<<<gb, 256, 0, stream>>>(ha, w2s, vsd2, xsb, al, n);
  k_gat_agg<<<ab, 256, 0, stream>>>(xsb, al, rowptr, col, b2, ha, n, 1);
  // layer 3
  k_lin3<<<gb, 256, 0, stream>>>(ha, u3, xsal3, n);
  k_agg3<<<(n + 255) / 256, 256, 0, stream>>>(xsal3, rowptr, col, b3, (float*)d_out, n);
}

// Round 5
// 450.007 us; speedup vs baseline: 1.1774x; 1.1774x over previous
//
#include <hip/hip_runtime.h>
#include <hip/hip_bf16.h>

#define LEAKY_ATT 0.2f
#define LEAKY_ACT 0.01f
#define BSHIFT 8
#define CH 4096

__device__ __forceinline__ float leaky(float x, float s) { return x >= 0.f ? x : s * x; }

__device__ __forceinline__ uint f2bf(float f) {
  __hip_bfloat16 h = __float2bfloat16(f);  // RTNE
  return (uint)*reinterpret_cast<ushort*>(&h);
}

__device__ __forceinline__ float bf_lo(uint q) { return __uint_as_float(q << 16); }
__device__ __forceinline__ float bf_hi(uint q) { return __uint_as_float(q & 0xffff0000u); }

// ============================ CSR build: two-level counting sort ============================
__global__ __launch_bounds__(256) void k_bhist(const int* __restrict__ dst, int e, int nb,
                                               int* __restrict__ bcnt) {
  __shared__ int cnt[512];
  for (int i = threadIdx.x; i < 512; i += 256) cnt[i] = 0;
  __syncthreads();
  for (int i = blockIdx.x * 256 + threadIdx.x; i < e; i += gridDim.x * 256)
    atomicAdd(&cnt[dst[i] >> BSHIFT], 1);
  __syncthreads();
  for (int i = threadIdx.x; i < nb; i += 256)
    if (cnt[i]) atomicAdd(&bcnt[i], cnt[i]);
}

__global__ __launch_bounds__(512) void k_bscan(const int* __restrict__ bcnt, int nb,
                                               int* __restrict__ bbase, int* __restrict__ bcur) {
  __shared__ int sh[512];
  int t = threadIdx.x;
  int orig = (t < nb) ? bcnt[t] : 0;
  sh[t] = orig;
  __syncthreads();
  for (int off = 1; off < 512; off <<= 1) {
    int v = (t >= off) ? sh[t - off] : 0;
    __syncthreads();
    sh[t] += v;
    __syncthreads();
  }
  if (t < nb) {
    int ex = sh[t] - orig;
    bbase[t] = ex;
    bcur[t] = ex;
    if (t == nb - 1) bbase[nb] = sh[t];
  }
}

__global__ __launch_bounds__(256) void k_bucket(const int* __restrict__ src,
                                                const int* __restrict__ dst, int e, int nb,
                                                int* __restrict__ bcur, uint* __restrict__ bpair) {
  __shared__ uint spair[CH];
  __shared__ ushort skey[CH];
  __shared__ ushort srank[CH];
  __shared__ int cnt[512];
  __shared__ int gb[512];
  int t = threadIdx.x;
  int c0 = blockIdx.x * CH;
  int cn = min(CH, e - c0);
  if (cn <= 0) return;
  for (int i = t; i < 512; i += 256) cnt[i] = 0;
  __syncthreads();
  for (int i = t; i < cn; i += 256) {
    int s = src[c0 + i];
    int d = dst[c0 + i];
    int k = d >> BSHIFT;
    spair[i] = ((uint)(d & ((1 << BSHIFT) - 1)) << 20) | (uint)s;
    skey[i] = (ushort)k;
    srank[i] = (ushort)atomicAdd(&cnt[k], 1);
  }
  __syncthreads();
  for (int k = t; k < nb; k += 256)
    gb[k] = cnt[k] ? atomicAdd(&bcur[k], cnt[k]) : 0;
  __syncthreads();
  for (int i = t; i < cn; i += 256) {
    bpair[gb[skey[i]] + srank[i]] = spair[i];
  }
}

__global__ __launch_bounds__(256) void k_csr(const uint* __restrict__ bpair,
                                             const int* __restrict__ bbase, int n,
                                             int* __restrict__ rowptr, int* __restrict__ col) {
  __shared__ int deg[256];
  __shared__ int cur[256];
  int b = blockIdx.x, t = threadIdx.x;
  int e0 = bbase[b], e1 = bbase[b + 1];
  deg[t] = 0;
  __syncthreads();
  for (int i = e0 + t; i < e1; i += 256)
    atomicAdd(&deg[bpair[i] >> 20], 1);
  __syncthreads();
  int v = deg[t];
  cur[t] = v;
  __syncthreads();
  for (int off = 1; off < 256; off <<= 1) {
    int u = (t >= off) ? cur[t - off] : 0;
    __syncthreads();
    cur[t] += u;
    __syncthreads();
  }
  int incl = cur[t];
  int gnode = b * 256 + t;
  if (gnode < n) rowptr[gnode + 1] = e0 + incl;
  if (b == 0 && t == 0) rowptr[0] = 0;
  __syncthreads();
  cur[t] = e0 + incl - v;
  __syncthreads();
  for (int i = e0 + t; i < e1; i += 256) {
    uint pk = bpair[i];
    int loc = pk >> 20;
    int p = atomicAdd(&cur[loc], 1);
    col[p] = (int)(pk & 0xFFFFFu);
  }
}

// ============================ weight prep ============================
__global__ void k_prep_vsd(const float* __restrict__ wsrc, const float* __restrict__ wdst,
                           const float* __restrict__ asrc, const float* __restrict__ adst,
                           float* __restrict__ vsd) {
  int k = blockIdx.x;
  int i = threadIdx.x;
  float s = 0.f;
  if (i < 8) {
    for (int c = 0; c < 16; ++c) s += wsrc[k * 128 + i * 16 + c] * asrc[i * 16 + c];
  } else {
    int h = i - 8;
    for (int c = 0; c < 16; ++c) s += wdst[k * 128 + h * 16 + c] * adst[h * 16 + c];
  }
  vsd[k * 16 + i] = s;
}

__global__ void k_prep_u3(const float* __restrict__ w3s, const float* __restrict__ w3d,
                          const float* __restrict__ a3s, const float* __restrict__ a3d,
                          float* __restrict__ U) {
  int k = blockIdx.x * blockDim.x + threadIdx.x;
  if (k >= 128) return;
  U[k * 4 + 0] = w3s[k * 2 + 0];
  U[k * 4 + 1] = w3s[k * 2 + 1];
  U[k * 4 + 2] = w3s[k * 2 + 0] * a3s[0] + w3s[k * 2 + 1] * a3s[1];
  U[k * 4 + 3] = w3d[k * 2 + 0] * a3d[0] + w3d[k * 2 + 1] * a3d[1];
}

// ============================ layer 1/2 linear: XSb(bf16) = X@W, AL = X@vsd ============================
__global__ __launch_bounds__(256) void k_gemm_xs_al(const float* __restrict__ X,
                                                    const float* __restrict__ W,
                                                    const float* __restrict__ VSD,
                                                    ushort* __restrict__ XSb,
                                                    float* __restrict__ AL, int n) {
  __shared__ float xt[64][128];
  int t = threadIdx.x;
  int row0 = blockIdx.x * 64;
  for (int i = t; i < 64 * 128; i += 256) {
    int r = i >> 7, c = i & 127;
    int gr = row0 + r;
    xt[r][c] = (gr < n) ? X[gr * 128 + c] : 0.f;
  }
  __syncthreads();

  int c0 = (t & 31) * 4;
  int r0 = (t >> 5) * 8;
  float acc[8][4] = {};
  for (int k = 0; k < 128; ++k) {
    float4 wv = *reinterpret_cast<const float4*>(&W[k * 128 + c0]);
#pragma unroll
    for (int i = 0; i < 8; ++i) {
      float xv = xt[r0 + i][k];
      acc[i][0] += xv * wv.x;
      acc[i][1] += xv * wv.y;
      acc[i][2] += xv * wv.z;
      acc[i][3] += xv * wv.w;
    }
  }
#pragma unroll
  for (int i = 0; i < 8; ++i) {
    int gr = row0 + r0 + i;
    if (gr < n) {
      uint lo = f2bf(acc[i][0]) | (f2bf(acc[i][1]) << 16);
      uint hi = f2bf(acc[i][2]) | (f2bf(acc[i][3]) << 16);
      *reinterpret_cast<uint2*>(&XSb[(size_t)gr * 128 + c0]) = make_uint2(lo, hi);
    }
  }

  int node = t >> 2;
  int j0 = (t & 3) * 4;
  float a[4] = {};
  for (int k = 0; k < 128; ++k) {
    float xv = xt[node][k];
#pragma unroll
    for (int j = 0; j < 4; ++j) a[j] += xv * VSD[k * 16 + j0 + j];
  }
  int gr = row0 + node;
  if (gr < n) {
#pragma unroll
    for (int j = 0; j < 4; ++j) AL[gr * 16 + j0 + j] = a[j];
  }
}

// ============================ layer 1/2 aggregation: wave-per-node, no LDS/barriers/inner-shfl ====
// lane: g = lane>>5 (edge parity), sub = lane&31 (channel quad c0=4*sub, head hd=sub>>2).
// Group g processes edges base+g, base+2+g. Weights computed redundantly per lane (no broadcast).
// Cross-group combine: 5x shfl_xor(.,32) once at the end.
__global__ __launch_bounds__(256) void k_gat_agg(const ushort* __restrict__ XSb,
                                                 const float* __restrict__ AL,
                                                 const int* __restrict__ rowptr,
                                                 const int* __restrict__ col,
                                                 const float* __restrict__ bias,
                                                 float* __restrict__ OUT, int n, int act) {
  int t = threadIdx.x;
  int lane = t & 63;
  int node = blockIdx.x * 4 + (t >> 6);
  if (node >= n) return;
  int sub = lane & 31;
  int g = lane >> 5;
  int hd = sub >> 2;
  int c0 = sub * 4;

  float ald = AL[(size_t)node * 16 + 8 + hd];

  // self loop: group 0 only (avoid double count); exp redundant per lane (1 VALU wave-instr)
  float w0 = __expf(leaky(AL[(size_t)node * 16 + hd] + ald, LEAKY_ATT));
  if (g != 0) w0 = 0.f;
  uint2 qs = *reinterpret_cast<const uint2*>(&XSb[(size_t)node * 128 + c0]);
  float acc0 = w0 * bf_lo(qs.x);
  float acc1 = w0 * bf_hi(qs.x);
  float acc2 = w0 * bf_lo(qs.y);
  float acc3 = w0 * bf_hi(qs.y);
  float den = w0;

  int beg = rowptr[node], end = rowptr[node + 1];
  int base = beg;
  // main: 4 edges per iter (2 per group) — 6 independent loads in flight
  for (; base + 4 <= end; base += 4) {
    int s0 = col[base + g];
    int s1 = col[base + 2 + g];
    float l0 = AL[(size_t)s0 * 16 + hd];
    float l1 = AL[(size_t)s1 * 16 + hd];
    uint2 q0 = *reinterpret_cast<const uint2*>(&XSb[(size_t)s0 * 128 + c0]);
    uint2 q1 = *reinterpret_cast<const uint2*>(&XSb[(size_t)s1 * 128 + c0]);
    float wa = __expf(leaky(l0 + ald, LEAKY_ATT));
    float wb = __expf(leaky(l1 + ald, LEAKY_ATT));
    acc0 += wa * bf_lo(q0.x);
    acc1 += wa * bf_hi(q0.x);
    acc2 += wa * bf_lo(q0.y);
    acc3 += wa * bf_hi(q0.y);
    den += wa;
    acc0 += wb * bf_lo(q1.x);
    acc1 += wb * bf_hi(q1.x);
    acc2 += wb * bf_lo(q1.y);
    acc3 += wb * bf_hi(q1.y);
    den += wb;
  }
  // remainder: up to 3 edges, 2 at a time with group masking
  for (; base < end; base += 2) {
    int idx = base + g;
    bool on = idx < end;
    int s = on ? col[idx] : node;
    float l = AL[(size_t)s * 16 + hd];
    uint2 q = *reinterpret_cast<const uint2*>(&XSb[(size_t)s * 128 + c0]);
    float w = on ? __expf(leaky(l + ald, LEAKY_ATT)) : 0.f;
    acc0 += w * bf_lo(q.x);
    acc1 += w * bf_hi(q.x);
    acc2 += w * bf_lo(q.y);
    acc3 += w * bf_hi(q.y);
    den += w;
  }

  // cross-group combine (one-shot, 5 shfl_xor)
  acc0 += __shfl_xor(acc0, 32);
  acc1 += __shfl_xor(acc1, 32);
  acc2 += __shfl_xor(acc2, 32);
  acc3 += __shfl_xor(acc3, 32);
  den += __shfl_xor(den, 32);

  if (g == 0) {
    float inv = 1.f / den;
    float4 bv = *reinterpret_cast<const float4*>(&bias[c0]);
    float4 r;
    r.x = acc0 * inv + bv.x;
    r.y = acc1 * inv + bv.y;
    r.z = acc2 * inv + bv.z;
    r.w = acc3 * inv + bv.w;
    if (act) {
      r.x = leaky(r.x, LEAKY_ACT);
      r.y = leaky(r.y, LEAKY_ACT);
      r.z = leaky(r.z, LEAKY_ACT);
      r.w = leaky(r.w, LEAKY_ACT);
    }
    *reinterpret_cast<float4*>(&OUT[(size_t)node * 128 + c0]) = r;
  }
}

// ============================ layer 3 ============================
__global__ __launch_bounds__(256) void k_lin3(const float* __restrict__ X,
                                              const float* __restrict__ U,
                                              float* __restrict__ XSAL3, int n) {
  __shared__ float xt[64][128];
  int t = threadIdx.x;
  int row0 = blockIdx.x * 64;
  for (int i = t; i < 64 * 128; i += 256) {
    int r = i >> 7, c = i & 127;
    int gr = row0 + r;
    xt[r][c] = (gr < n) ? X[gr * 128 + c] : 0.f;
  }
  __syncthreads();
  int node = t >> 2;
  int j = t & 3;
  float a = 0.f;
  for (int k = 0; k < 128; ++k) a += xt[node][k] * U[k * 4 + j];
  int gr = row0 + node;
  if (gr < n) XSAL3[gr * 4 + j] = a;
}

__global__ __launch_bounds__(256) void k_agg3(const float* __restrict__ XSAL3,
                                              const int* __restrict__ rowptr,
                                              const int* __restrict__ col,
                                              const float* __restrict__ b3,
                                              float* __restrict__ out, int n) {
  int node = blockIdx.x * blockDim.x + threadIdx.x;
  if (node >= n) return;
  float4 self = *reinterpret_cast<const float4*>(&XSAL3[node * 4]);
  float ald = self.w;
  float e0 = leaky(self.z + ald, LEAKY_ATT);
  float w0 = __expf(e0);
  float den = w0;
  float a0 = w0 * self.x;
  float a1 = w0 * self.y;
  int end = rowptr[node + 1];
  for (int jj = rowptr[node]; jj < end; ++jj) {
    int s = col[jj];
    float4 v = *reinterpret_cast<const float4*>(&XSAL3[s * 4]);
    float ee = leaky(v.z + ald, LEAKY_ATT);
    float w = __expf(ee);
    den += w;
    a0 += w * v.x;
    a1 += w * v.y;
  }
  out[node * 2 + 0] = a0 / den + b3[0];
  out[node * 2 + 1] = a1 / den + b3[1];
}

// ============================ launch ============================
extern "C" void kernel_launch(void* const* d_in, const int* in_sizes, int n_in,
                              void* d_out, int out_size, void* d_ws, size_t ws_size,
                              hipStream_t stream) {
  const float* x = (const float*)d_in[0];
  const int* ei = (const int*)d_in[1];
  const float* w1s = (const float*)d_in[2];
  const float* w1d = (const float*)d_in[3];
  const float* a1s = (const float*)d_in[4];
  const float* a1d = (const float*)d_in[5];
  const float* b1 = (const float*)d_in[6];
  const float* w2s = (const float*)d_in[7];
  const float* w2d = (const float*)d_in[8];
  const float* a2s = (const float*)d_in[9];
  const float* a2d = (const float*)d_in[10];
  const float* b2 = (const float*)d_in[11];
  const float* w3s = (const float*)d_in[12];
  const float* w3d = (const float*)d_in[13];
  const float* a3s = (const float*)d_in[14];
  const float* a3d = (const float*)d_in[15];
  const float* b3 = (const float*)d_in[16];

  int n = in_sizes[0] / 128;
  int e = in_sizes[1] / 2;
  const int* srcp = ei;
  const int* dstp = ei + e;

  int nb = (n + 255) >> BSHIFT;
  if (nb > 512) return;
  if (n >= (1 << 20)) return;

  size_t off = 0;
  auto alloc = [&](size_t bytes) -> void* {
    void* p = (char*)d_ws + off;
    off += (bytes + 255) & ~(size_t)255;
    return p;
  };
  int* bcnt = (int*)alloc((size_t)(nb) * 4);
  int* bbase = (int*)alloc((size_t)(nb + 1) * 4);
  int* bcur = (int*)alloc((size_t)nb * 4);
  uint* bpair = (uint*)alloc((size_t)e * 4);
  int* rowptr = (int*)alloc((size_t)(n + 1) * 4);
  int* col = (int*)alloc((size_t)e * 4);
  float* vsd1 = (float*)alloc(128 * 16 * 4);
  float* vsd2 = (float*)alloc(128 * 16 * 4);
  float* u3 = (float*)alloc(128 * 4 * 4);
  float* al = (float*)alloc((size_t)n * 16 * 4);
  ushort* xsb = (ushort*)alloc((size_t)n * 128 * 2);
  float* ha = (float*)alloc((size_t)n * 128 * 4);
  float* xsal3 = (float*)alloc((size_t)n * 4 * 4);
  if (off > ws_size) return;

  hipMemsetAsync(bcnt, 0, (size_t)nb * 4, stream);
  k_bhist<<<512, 256, 0, stream>>>(dstp, e, nb, bcnt);
  k_bscan<<<1, 512, 0, stream>>>(bcnt, nb, bbase, bcur);
  k_bucket<<<(e + CH - 1) / CH, 256, 0, stream>>>(srcp, dstp, e, nb, bcur, bpair);
  k_csr<<<nb, 256, 0, stream>>>(bpair, bbase, n, rowptr, col);

  k_prep_vsd<<<128, 16, 0, stream>>>(w1s, w1d, a1s, a1d, vsd1);
  k_prep_vsd<<<128, 16, 0, stream>>>(w2s, w2d, a2s, a2d, vsd2);
  k_prep_u3<<<1, 128, 0, stream>>>(w3s, w3d, a3s, a3d, u3);

  int gb = (n + 63) / 64;
  int ab = (n + 3) / 4;
  // layer 1
  k_gemm_xs_al<<<gb, 256, 0, stream>>>(x, w1s, vsd1, xsb, al, n);
  k_gat_agg<<<ab, 256, 0, stream>>>(xsb, al, rowptr, col, b1, ha, n, 1);
  // layer 2
  k_gemm_xs_al<<<gb, 256, 0, stream>>>(ha, w2s, vsd2, xsb, al, n);
  k_gat_agg<<<ab, 256, 0, stream>>>(xsb, al, rowptr, col, b2, ha, n, 1);
  // layer 3
  k_lin3<<<gb, 256, 0, stream>>>(ha, u3, xsal3, n);
  k_agg3<<<(n + 255) / 256, 256, 0, stream>>>(xsal3, rowptr, col, b3, (float*)d_out, n);
}

// Round 6
// 309.728 us; speedup vs baseline: 1.7107x; 1.4529x over previous
//
#include <hip/hip_runtime.h>
#include <hip/hip_bf16.h>

#define LEAKY_ATT 0.2f
#define LEAKY_ACT 0.01f
#define BSHIFT 8
#define CH 4096

typedef __attribute__((ext_vector_type(8))) short bf16x8;
typedef __attribute__((ext_vector_type(4))) float f32x4;

__device__ __forceinline__ float leaky(float x, float s) { return x >= 0.f ? x : s * x; }

__device__ __forceinline__ uint f2bf(float f) {
  __hip_bfloat16 h = __float2bfloat16(f);  // RTNE
  return (uint)*reinterpret_cast<ushort*>(&h);
}

__device__ __forceinline__ float bf_lo(uint q) { return __uint_as_float(q << 16); }
__device__ __forceinline__ float bf_hi(uint q) { return __uint_as_float(q & 0xffff0000u); }

// ============================ CSR build: two-level counting sort ============================
__global__ __launch_bounds__(256) void k_bhist(const int* __restrict__ dst, int e, int nb,
                                               int* __restrict__ bcnt) {
  __shared__ int cnt[512];
  for (int i = threadIdx.x; i < 512; i += 256) cnt[i] = 0;
  __syncthreads();
  for (int i = blockIdx.x * 256 + threadIdx.x; i < e; i += gridDim.x * 256)
    atomicAdd(&cnt[dst[i] >> BSHIFT], 1);
  __syncthreads();
  for (int i = threadIdx.x; i < nb; i += 256)
    if (cnt[i]) atomicAdd(&bcnt[i], cnt[i]);
}

__global__ __launch_bounds__(512) void k_bscan(const int* __restrict__ bcnt, int nb,
                                               int* __restrict__ bbase, int* __restrict__ bcur) {
  __shared__ int sh[512];
  int t = threadIdx.x;
  int orig = (t < nb) ? bcnt[t] : 0;
  sh[t] = orig;
  __syncthreads();
  for (int off = 1; off < 512; off <<= 1) {
    int v = (t >= off) ? sh[t - off] : 0;
    __syncthreads();
    sh[t] += v;
    __syncthreads();
  }
  if (t < nb) {
    int ex = sh[t] - orig;
    bbase[t] = ex;
    bcur[t] = ex;
    if (t == nb - 1) bbase[nb] = sh[t];
  }
}

__global__ __launch_bounds__(256) void k_bucket(const int* __restrict__ src,
                                                const int* __restrict__ dst, int e, int nb,
                                                int* __restrict__ bcur, uint* __restrict__ bpair) {
  __shared__ uint spair[CH];
  __shared__ ushort skey[CH];
  __shared__ ushort srank[CH];
  __shared__ int cnt[512];
  __shared__ int gb[512];
  int t = threadIdx.x;
  int c0 = blockIdx.x * CH;
  int cn = min(CH, e - c0);
  if (cn <= 0) return;
  for (int i = t; i < 512; i += 256) cnt[i] = 0;
  __syncthreads();
  for (int i = t; i < cn; i += 256) {
    int s = src[c0 + i];
    int d = dst[c0 + i];
    int k = d >> BSHIFT;
    spair[i] = ((uint)(d & ((1 << BSHIFT) - 1)) << 20) | (uint)s;
    skey[i] = (ushort)k;
    srank[i] = (ushort)atomicAdd(&cnt[k], 1);
  }
  __syncthreads();
  for (int k = t; k < nb; k += 256)
    gb[k] = cnt[k] ? atomicAdd(&bcur[k], cnt[k]) : 0;
  __syncthreads();
  for (int i = t; i < cn; i += 256) {
    bpair[gb[skey[i]] + srank[i]] = spair[i];
  }
}

__global__ __launch_bounds__(256) void k_csr(const uint* __restrict__ bpair,
                                             const int* __restrict__ bbase, int n,
                                             int* __restrict__ rowptr, int* __restrict__ col) {
  __shared__ int deg[256];
  __shared__ int cur[256];
  int b = blockIdx.x, t = threadIdx.x;
  int e0 = bbase[b], e1 = bbase[b + 1];
  deg[t] = 0;
  __syncthreads();
  for (int i = e0 + t; i < e1; i += 256)
    atomicAdd(&deg[bpair[i] >> 20], 1);
  __syncthreads();
  int v = deg[t];
  cur[t] = v;
  __syncthreads();
  for (int off = 1; off < 256; off <<= 1) {
    int u = (t >= off) ? cur[t - off] : 0;
    __syncthreads();
    cur[t] += u;
    __syncthreads();
  }
  int incl = cur[t];
  int gnode = b * 256 + t;
  if (gnode < n) rowptr[gnode + 1] = e0 + incl;
  if (b == 0 && t == 0) rowptr[0] = 0;
  __syncthreads();
  cur[t] = e0 + incl - v;
  __syncthreads();
  for (int i = e0 + t; i < e1; i += 256) {
    uint pk = bpair[i];
    int loc = pk >> 20;
    int p = atomicAdd(&cur[loc], 1);
    col[p] = (int)(pk & 0xFFFFFu);
  }
}

// ============================ weight prep ============================
__global__ void k_prep_vsd(const float* __restrict__ wsrc, const float* __restrict__ wdst,
                           const float* __restrict__ asrc, const float* __restrict__ adst,
                           float* __restrict__ vsd) {
  int k = blockIdx.x;
  int i = threadIdx.x;
  float s = 0.f;
  if (i < 8) {
    for (int c = 0; c < 16; ++c) s += wsrc[k * 128 + i * 16 + c] * asrc[i * 16 + c];
  } else {
    int h = i - 8;
    for (int c = 0; c < 16; ++c) s += wdst[k * 128 + h * 16 + c] * adst[h * 16 + c];
  }
  vsd[k * 16 + i] = s;
}

__global__ void k_prep_u3(const float* __restrict__ w3s, const float* __restrict__ w3d,
                          const float* __restrict__ a3s, const float* __restrict__ a3d,
                          float* __restrict__ U) {
  int k = blockIdx.x * blockDim.x + threadIdx.x;
  if (k >= 128) return;
  U[k * 4 + 0] = w3s[k * 2 + 0];
  U[k * 4 + 1] = w3s[k * 2 + 1];
  U[k * 4 + 2] = w3s[k * 2 + 0] * a3s[0] + w3s[k * 2 + 1] * a3s[1];
  U[k * 4 + 3] = w3d[k * 2 + 0] * a3d[0] + w3d[k * 2 + 1] * a3d[1];
}

// B-fragment pre-swizzle: 9 col-tiles (8 W + 1 VSD) x 4 ksteps; lane l holds
// B[k = ks*32 + (l>>4)*8 + j][c = ct*16 + (l&15)], 8 bf16 contiguous per lane.
__global__ __launch_bounds__(64) void k_prep_frag(const float* __restrict__ W,
                                                  const float* __restrict__ VSD,
                                                  ushort* __restrict__ WF) {
  int blk = blockIdx.x;  // ct*4+ks, 36 blocks
  int lane = threadIdx.x;
  int ct = blk >> 2, ks = blk & 3;
  uint out[4];
#pragma unroll
  for (int jj = 0; jj < 8; ++jj) {
    int k = ks * 32 + (lane >> 4) * 8 + jj;
    int c = ct * 16 + (lane & 15);
    float v = (c < 128) ? W[k * 128 + c] : VSD[k * 16 + (c - 128)];
    ((ushort*)out)[jj] = (ushort)f2bf(v);
  }
  *reinterpret_cast<uint4*>(&WF[(size_t)(blk * 64 + lane) * 8]) = *reinterpret_cast<uint4*>(out);
}

// ============================ MFMA GEMM: [XSb | AL] = Xtile @ [W | VSD] ============================
// block: 256 thr = 4 waves; tile 64 nodes x 144 cols; K=128.
// A in LDS bf16, XOR-swizzled (byte ^= (row&7)<<4). B-frags from pre-swizzled global.
template <int INMODE>  // 0: fp32 X, 1: bf16 X
__global__ __launch_bounds__(256) void k_gemm_mfma(const void* __restrict__ Xv,
                                                   const ushort* __restrict__ WF,
                                                   ushort* __restrict__ XSb,
                                                   float* __restrict__ AL, int n) {
  __shared__ __align__(16) char xt[16384];  // 64 rows x 128 k bf16
  int t = threadIdx.x;
  int row0 = blockIdx.x * 64;

  if (INMODE == 0) {
    const float* X = (const float*)Xv;
#pragma unroll
    for (int i = 0; i < 8; ++i) {
      int flat = (i * 256 + t) * 4;
      int r = flat >> 7, k0 = flat & 127;
      int gr = row0 + r;
      float4 v = (gr < n) ? *reinterpret_cast<const float4*>(&X[(size_t)gr * 128 + k0])
                          : make_float4(0.f, 0.f, 0.f, 0.f);
      uint lo = f2bf(v.x) | (f2bf(v.y) << 16);
      uint hi = f2bf(v.z) | (f2bf(v.w) << 16);
      int byte = (r * 256 + k0 * 2) ^ ((r & 7) << 4);
      *reinterpret_cast<uint2*>(xt + byte) = make_uint2(lo, hi);
    }
  } else {
    const ushort* X = (const ushort*)Xv;
#pragma unroll
    for (int i = 0; i < 4; ++i) {
      int flat = (i * 256 + t) * 8;
      int r = flat >> 7, k0 = flat & 127;
      int gr = row0 + r;
      uint4 v = (gr < n) ? *reinterpret_cast<const uint4*>(&X[(size_t)gr * 128 + k0])
                         : make_uint4(0u, 0u, 0u, 0u);
      int byte = (r * 256 + k0 * 2) ^ ((r & 7) << 4);
      *reinterpret_cast<uint4*>(xt + byte) = v;
    }
  }
  __syncthreads();

  int wave = t >> 6;
  int lane = t & 63;
  int arow = wave * 16 + (lane & 15);
  int kgrp = (lane >> 4) * 8;

  bf16x8 afrag[4];
#pragma unroll
  for (int ks = 0; ks < 4; ++ks) {
    int kb = ks * 32 + kgrp;
    int byte = (arow * 256 + kb * 2) ^ ((arow & 7) << 4);
    afrag[ks] = *reinterpret_cast<const bf16x8*>(xt + byte);
  }

  f32x4 acc[9];
#pragma unroll
  for (int ct = 0; ct < 9; ++ct) {
    f32x4 a = {0.f, 0.f, 0.f, 0.f};
#pragma unroll
    for (int ks = 0; ks < 4; ++ks) {
      bf16x8 b = *reinterpret_cast<const bf16x8*>(&WF[(size_t)((ct * 4 + ks) * 64 + lane) * 8]);
      a = __builtin_amdgcn_mfma_f32_16x16x32_bf16(afrag[ks], b, a, 0, 0, 0);
    }
    acc[ct] = a;
  }

  // stores: D col = ct*16 + (lane&15), row = wave*16 + (lane>>4)*4 + i
  int rbase = wave * 16 + (lane >> 4) * 4;
  int csub = lane & 15;
#pragma unroll
  for (int ct = 0; ct < 8; ++ct) {
#pragma unroll
    for (int i = 0; i < 4; ++i) {
      int gr = row0 + rbase + i;
      if (gr < n) XSb[(size_t)gr * 128 + ct * 16 + csub] = (ushort)f2bf(acc[ct][i]);
    }
  }
#pragma unroll
  for (int i = 0; i < 4; ++i) {
    int gr = row0 + rbase + i;
    if (gr < n) AL[(size_t)gr * 16 + csub] = acc[8][i];
  }
}

// ============================ layer 1/2 aggregation: wave-per-node ============================
// MODE 1: write bf16 activations HB. MODE 2: fused lin3 -> XSAL3[n][4] (needs U).
template <int MODE>
__global__ __launch_bounds__(256) void k_gat_agg(const ushort* __restrict__ XSb,
                                                 const float* __restrict__ AL,
                                                 const int* __restrict__ rowptr,
                                                 const int* __restrict__ col,
                                                 const float* __restrict__ bias,
                                                 void* __restrict__ OUTv,
                                                 const float* __restrict__ U, int n) {
  int t = threadIdx.x;
  int lane = t & 63;
  int node = blockIdx.x * 4 + (t >> 6);
  if (node >= n) return;
  int sub = lane & 31;
  int g = lane >> 5;
  int hd = sub >> 2;
  int c0 = sub * 4;

  float ald = AL[(size_t)node * 16 + 8 + hd];

  float w0 = __expf(leaky(AL[(size_t)node * 16 + hd] + ald, LEAKY_ATT));
  if (g != 0) w0 = 0.f;
  uint2 qs = *reinterpret_cast<const uint2*>(&XSb[(size_t)node * 128 + c0]);
  float acc0 = w0 * bf_lo(qs.x);
  float acc1 = w0 * bf_hi(qs.x);
  float acc2 = w0 * bf_lo(qs.y);
  float acc3 = w0 * bf_hi(qs.y);
  float den = w0;

  int beg = rowptr[node], end = rowptr[node + 1];
  int base = beg;
  for (; base + 4 <= end; base += 4) {
    int s0 = col[base + g];
    int s1 = col[base + 2 + g];
    float l0 = AL[(size_t)s0 * 16 + hd];
    float l1 = AL[(size_t)s1 * 16 + hd];
    uint2 q0 = *reinterpret_cast<const uint2*>(&XSb[(size_t)s0 * 128 + c0]);
    uint2 q1 = *reinterpret_cast<const uint2*>(&XSb[(size_t)s1 * 128 + c0]);
    float wa = __expf(leaky(l0 + ald, LEAKY_ATT));
    float wb = __expf(leaky(l1 + ald, LEAKY_ATT));
    acc0 += wa * bf_lo(q0.x);
    acc1 += wa * bf_hi(q0.x);
    acc2 += wa * bf_lo(q0.y);
    acc3 += wa * bf_hi(q0.y);
    den += wa;
    acc0 += wb * bf_lo(q1.x);
    acc1 += wb * bf_hi(q1.x);
    acc2 += wb * bf_lo(q1.y);
    acc3 += wb * bf_hi(q1.y);
    den += wb;
  }
  for (; base < end; base += 2) {
    int idx = base + g;
    bool on = idx < end;
    int s = on ? col[idx] : node;
    float l = AL[(size_t)s * 16 + hd];
    uint2 q = *reinterpret_cast<const uint2*>(&XSb[(size_t)s * 128 + c0]);
    float w = on ? __expf(leaky(l + ald, LEAKY_ATT)) : 0.f;
    acc0 += w * bf_lo(q.x);
    acc1 += w * bf_hi(q.x);
    acc2 += w * bf_lo(q.y);
    acc3 += w * bf_hi(q.y);
    den += w;
  }

  acc0 += __shfl_xor(acc0, 32);
  acc1 += __shfl_xor(acc1, 32);
  acc2 += __shfl_xor(acc2, 32);
  acc3 += __shfl_xor(acc3, 32);
  den += __shfl_xor(den, 32);

  if (g == 0) {
    float inv = 1.f / den;
    float4 bv = *reinterpret_cast<const float4*>(&bias[c0]);
    float r0 = leaky(acc0 * inv + bv.x, LEAKY_ACT);
    float r1 = leaky(acc1 * inv + bv.y, LEAKY_ACT);
    float r2 = leaky(acc2 * inv + bv.z, LEAKY_ACT);
    float r3 = leaky(acc3 * inv + bv.w, LEAKY_ACT);
    if (MODE == 1) {
      ushort* HB = (ushort*)OUTv;
      uint lo = f2bf(r0) | (f2bf(r1) << 16);
      uint hi = f2bf(r2) | (f2bf(r3) << 16);
      *reinterpret_cast<uint2*>(&HB[(size_t)node * 128 + c0]) = make_uint2(lo, hi);
    } else {
      float rr[4] = {r0, r1, r2, r3};
      float p0 = 0.f, p1 = 0.f, p2 = 0.f, p3 = 0.f;
#pragma unroll
      for (int c = 0; c < 4; ++c) {
        float4 uv = *reinterpret_cast<const float4*>(&U[(c0 + c) * 4]);
        p0 += rr[c] * uv.x;
        p1 += rr[c] * uv.y;
        p2 += rr[c] * uv.z;
        p3 += rr[c] * uv.w;
      }
#pragma unroll
      for (int m = 1; m < 32; m <<= 1) {
        p0 += __shfl_xor(p0, m);
        p1 += __shfl_xor(p1, m);
        p2 += __shfl_xor(p2, m);
        p3 += __shfl_xor(p3, m);
      }
      if (sub == 0) {
        float* X3 = (float*)OUTv;
        *reinterpret_cast<float4*>(&X3[(size_t)node * 4]) = make_float4(p0, p1, p2, p3);
      }
    }
  }
}

// ============================ layer 3 aggregation ============================
__global__ __launch_bounds__(256) void k_agg3(const float* __restrict__ XSAL3,
                                              const int* __restrict__ rowptr,
                                              const int* __restrict__ col,
                                              const float* __restrict__ b3,
                                              float* __restrict__ out, int n) {
  int node = blockIdx.x * blockDim.x + threadIdx.x;
  if (node >= n) return;
  float4 self = *reinterpret_cast<const float4*>(&XSAL3[node * 4]);
  float ald = self.w;
  float e0 = leaky(self.z + ald, LEAKY_ATT);
  float w0 = __expf(e0);
  float den = w0;
  float a0 = w0 * self.x;
  float a1 = w0 * self.y;
  int end = rowptr[node + 1];
  for (int jj = rowptr[node]; jj < end; ++jj) {
    int s = col[jj];
    float4 v = *reinterpret_cast<const float4*>(&XSAL3[s * 4]);
    float ee = leaky(v.z + ald, LEAKY_ATT);
    float w = __expf(ee);
    den += w;
    a0 += w * v.x;
    a1 += w * v.y;
  }
  out[node * 2 + 0] = a0 / den + b3[0];
  out[node * 2 + 1] = a1 / den + b3[1];
}

// ============================ launch ============================
extern "C" void kernel_launch(void* const* d_in, const int* in_sizes, int n_in,
                              void* d_out, int out_size, void* d_ws, size_t ws_size,
                              hipStream_t stream) {
  const float* x = (const float*)d_in[0];
  const int* ei = (const int*)d_in[1];
  const float* w1s = (const float*)d_in[2];
  const float* w1d = (const float*)d_in[3];
  const float* a1s = (const float*)d_in[4];
  const float* a1d = (const float*)d_in[5];
  const float* b1 = (const float*)d_in[6];
  const float* w2s = (const float*)d_in[7];
  const float* w2d = (const float*)d_in[8];
  const float* a2s = (const float*)d_in[9];
  const float* a2d = (const float*)d_in[10];
  const float* b2 = (const float*)d_in[11];
  const float* w3s = (const float*)d_in[12];
  const float* w3d = (const float*)d_in[13];
  const float* a3s = (const float*)d_in[14];
  const float* a3d = (const float*)d_in[15];
  const float* b3 = (const float*)d_in[16];

  int n = in_sizes[0] / 128;
  int e = in_sizes[1] / 2;
  const int* srcp = ei;
  const int* dstp = ei + e;

  int nb = (n + 255) >> BSHIFT;
  if (nb > 512) return;
  if (n >= (1 << 20)) return;

  size_t off = 0;
  auto alloc = [&](size_t bytes) -> void* {
    void* p = (char*)d_ws + off;
    off += (bytes + 255) & ~(size_t)255;
    return p;
  };
  int* bcnt = (int*)alloc((size_t)nb * 4);
  int* bbase = (int*)alloc((size_t)(nb + 1) * 4);
  int* bcur = (int*)alloc((size_t)nb * 4);
  uint* bpair = (uint*)alloc((size_t)e * 4);
  int* rowptr = (int*)alloc((size_t)(n + 1) * 4);
  int* col = (int*)alloc((size_t)e * 4);
  float* vsd1 = (float*)alloc(128 * 16 * 4);
  float* vsd2 = (float*)alloc(128 * 16 * 4);
  float* u3 = (float*)alloc(128 * 4 * 4);
  ushort* wf1 = (ushort*)alloc(36 * 64 * 8 * 2);
  ushort* wf2 = (ushort*)alloc(36 * 64 * 8 * 2);
  float* al = (float*)alloc((size_t)n * 16 * 4);
  ushort* xsb = (ushort*)alloc((size_t)n * 128 * 2);
  ushort* hb = (ushort*)alloc((size_t)n * 128 * 2);
  float* xsal3 = (float*)alloc((size_t)n * 4 * 4);
  if (off > ws_size) return;

  // CSR build
  hipMemsetAsync(bcnt, 0, (size_t)nb * 4, stream);
  k_bhist<<<512, 256, 0, stream>>>(dstp, e, nb, bcnt);
  k_bscan<<<1, 512, 0, stream>>>(bcnt, nb, bbase, bcur);
  k_bucket<<<(e + CH - 1) / CH, 256, 0, stream>>>(srcp, dstp, e, nb, bcur, bpair);
  k_csr<<<nb, 256, 0, stream>>>(bpair, bbase, n, rowptr, col);

  // weight prep
  k_prep_vsd<<<128, 16, 0, stream>>>(w1s, w1d, a1s, a1d, vsd1);
  k_prep_vsd<<<128, 16, 0, stream>>>(w2s, w2d, a2s, a2d, vsd2);
  k_prep_u3<<<1, 128, 0, stream>>>(w3s, w3d, a3s, a3d, u3);
  k_prep_frag<<<36, 64, 0, stream>>>(w1s, vsd1, wf1);
  k_prep_frag<<<36, 64, 0, stream>>>(w2s, vsd2, wf2);

  int gb = (n + 63) / 64;
  int ab = (n + 3) / 4;
  // layer 1
  k_gemm_mfma<0><<<gb, 256, 0, stream>>>(x, wf1, xsb, al, n);
  k_gat_agg<1><<<ab, 256, 0, stream>>>(xsb, al, rowptr, col, b1, hb, nullptr, n);
  // layer 2 (+fused lin3)
  k_gemm_mfma<1><<<gb, 256, 0, stream>>>(hb, wf2, xsb, al, n);
  k_gat_agg<2><<<ab, 256, 0, stream>>>(xsb, al, rowptr, col, b2, xsal3, u3, n);
  // layer 3
  k_agg3<<<(n + 255) / 256, 256, 0, stream>>>(xsal3, rowptr, col, b3, (float*)d_out, n);
}

// Round 7
// 297.185 us; speedup vs baseline: 1.7829x; 1.0422x over previous
//
#include <hip/hip_runtime.h>
#include <hip/hip_bf16.h>

#define LEAKY_ATT 0.2f
#define LEAKY_ACT 0.01f
#define BSHIFT 8
#define CH 4096

typedef __attribute__((ext_vector_type(8))) short bf16x8;
typedef __attribute__((ext_vector_type(4))) float f32x4;

__device__ __forceinline__ float lrelu(float x, float s) { return fmaxf(x, s * x); }

__device__ __forceinline__ uint f2bf(float f) {
  __hip_bfloat16 h = __float2bfloat16(f);  // RTNE
  return (uint)*reinterpret_cast<ushort*>(&h);
}

__device__ __forceinline__ float bf_lo(uint q) { return __uint_as_float(q << 16); }
__device__ __forceinline__ float bf_hi(uint q) { return __uint_as_float(q & 0xffff0000u); }

// ============================ CSR build: two-level counting sort ============================
__global__ __launch_bounds__(256) void k_bhist(const int* __restrict__ dst, int e, int nb,
                                               int* __restrict__ bcnt) {
  __shared__ int cnt[512];
  for (int i = threadIdx.x; i < 512; i += 256) cnt[i] = 0;
  __syncthreads();
  for (int i = blockIdx.x * 256 + threadIdx.x; i < e; i += gridDim.x * 256)
    atomicAdd(&cnt[dst[i] >> BSHIFT], 1);
  __syncthreads();
  for (int i = threadIdx.x; i < nb; i += 256)
    if (cnt[i]) atomicAdd(&bcnt[i], cnt[i]);
}

__global__ __launch_bounds__(512) void k_bscan(const int* __restrict__ bcnt, int nb,
                                               int* __restrict__ bbase, int* __restrict__ bcur) {
  __shared__ int sh[512];
  int t = threadIdx.x;
  int orig = (t < nb) ? bcnt[t] : 0;
  sh[t] = orig;
  __syncthreads();
  for (int off = 1; off < 512; off <<= 1) {
    int v = (t >= off) ? sh[t - off] : 0;
    __syncthreads();
    sh[t] += v;
    __syncthreads();
  }
  if (t < nb) {
    int ex = sh[t] - orig;
    bbase[t] = ex;
    bcur[t] = ex;
    if (t == nb - 1) bbase[nb] = sh[t];
  }
}

__global__ __launch_bounds__(256) void k_bucket(const int* __restrict__ src,
                                                const int* __restrict__ dst, int e, int nb,
                                                int* __restrict__ bcur, uint* __restrict__ bpair) {
  __shared__ uint spair[CH];
  __shared__ ushort skey[CH];
  __shared__ ushort srank[CH];
  __shared__ int cnt[512];
  __shared__ int gb[512];
  int t = threadIdx.x;
  int c0 = blockIdx.x * CH;
  int cn = min(CH, e - c0);
  if (cn <= 0) return;
  for (int i = t; i < 512; i += 256) cnt[i] = 0;
  __syncthreads();
  for (int i = t; i < cn; i += 256) {
    int s = src[c0 + i];
    int d = dst[c0 + i];
    int k = d >> BSHIFT;
    spair[i] = ((uint)(d & ((1 << BSHIFT) - 1)) << 20) | (uint)s;
    skey[i] = (ushort)k;
    srank[i] = (ushort)atomicAdd(&cnt[k], 1);
  }
  __syncthreads();
  for (int k = t; k < nb; k += 256)
    gb[k] = cnt[k] ? atomicAdd(&bcur[k], cnt[k]) : 0;
  __syncthreads();
  for (int i = t; i < cn; i += 256) {
    bpair[gb[skey[i]] + srank[i]] = spair[i];
  }
}

__global__ __launch_bounds__(256) void k_csr(const uint* __restrict__ bpair,
                                             const int* __restrict__ bbase, int n,
                                             int* __restrict__ rowptr, int* __restrict__ col) {
  __shared__ int deg[256];
  __shared__ int cur[256];
  int b = blockIdx.x, t = threadIdx.x;
  int e0 = bbase[b], e1 = bbase[b + 1];
  deg[t] = 0;
  __syncthreads();
  for (int i = e0 + t; i < e1; i += 256)
    atomicAdd(&deg[bpair[i] >> 20], 1);
  __syncthreads();
  int v = deg[t];
  cur[t] = v;
  __syncthreads();
  for (int off = 1; off < 256; off <<= 1) {
    int u = (t >= off) ? cur[t - off] : 0;
    __syncthreads();
    cur[t] += u;
    __syncthreads();
  }
  int incl = cur[t];
  int gnode = b * 256 + t;
  if (gnode < n) rowptr[gnode + 1] = e0 + incl;
  if (b == 0 && t == 0) rowptr[0] = 0;
  __syncthreads();
  cur[t] = e0 + incl - v;
  __syncthreads();
  for (int i = e0 + t; i < e1; i += 256) {
    uint pk = bpair[i];
    int loc = pk >> 20;
    int p = atomicAdd(&cur[loc], 1);
    col[p] = (int)(pk & 0xFFFFFu);
  }
}

// ============================ weight prep ============================
__global__ void k_prep_vsd(const float* __restrict__ wsrc, const float* __restrict__ wdst,
                           const float* __restrict__ asrc, const float* __restrict__ adst,
                           float* __restrict__ vsd) {
  int k = blockIdx.x;
  int i = threadIdx.x;
  float s = 0.f;
  if (i < 8) {
    for (int c = 0; c < 16; ++c) s += wsrc[k * 128 + i * 16 + c] * asrc[i * 16 + c];
  } else {
    int h = i - 8;
    for (int c = 0; c < 16; ++c) s += wdst[k * 128 + h * 16 + c] * adst[h * 16 + c];
  }
  vsd[k * 16 + i] = s;
}

__global__ void k_prep_u3(const float* __restrict__ w3s, const float* __restrict__ w3d,
                          const float* __restrict__ a3s, const float* __restrict__ a3d,
                          float* __restrict__ U) {
  int k = blockIdx.x * blockDim.x + threadIdx.x;
  if (k >= 128) return;
  U[k * 4 + 0] = w3s[k * 2 + 0];
  U[k * 4 + 1] = w3s[k * 2 + 1];
  U[k * 4 + 2] = w3s[k * 2 + 0] * a3s[0] + w3s[k * 2 + 1] * a3s[1];
  U[k * 4 + 3] = w3d[k * 2 + 0] * a3d[0] + w3d[k * 2 + 1] * a3d[1];
}

// B-fragment pre-swizzle (see R6 notes)
__global__ __launch_bounds__(64) void k_prep_frag(const float* __restrict__ W,
                                                  const float* __restrict__ VSD,
                                                  ushort* __restrict__ WF) {
  int blk = blockIdx.x;  // ct*4+ks, 36 blocks
  int lane = threadIdx.x;
  int ct = blk >> 2, ks = blk & 3;
  uint out[4];
#pragma unroll
  for (int jj = 0; jj < 8; ++jj) {
    int k = ks * 32 + (lane >> 4) * 8 + jj;
    int c = ct * 16 + (lane & 15);
    float v = (c < 128) ? W[k * 128 + c] : VSD[k * 16 + (c - 128)];
    ((ushort*)out)[jj] = (ushort)f2bf(v);
  }
  *reinterpret_cast<uint4*>(&WF[(size_t)(blk * 64 + lane) * 8]) = *reinterpret_cast<uint4*>(out);
}

// ============================ MFMA GEMM: [XSb | AL] = Xtile @ [W | VSD] ============================
template <int INMODE>  // 0: fp32 X, 1: bf16 X
__global__ __launch_bounds__(256) void k_gemm_mfma(const void* __restrict__ Xv,
                                                   const ushort* __restrict__ WF,
                                                   ushort* __restrict__ XSb,
                                                   float* __restrict__ AL, int n) {
  __shared__ __align__(16) char xt[16384];  // 64 rows x 128 k bf16
  int t = threadIdx.x;
  int row0 = blockIdx.x * 64;

  if (INMODE == 0) {
    const float* X = (const float*)Xv;
#pragma unroll
    for (int i = 0; i < 8; ++i) {
      int flat = (i * 256 + t) * 4;
      int r = flat >> 7, k0 = flat & 127;
      int gr = row0 + r;
      float4 v = (gr < n) ? *reinterpret_cast<const float4*>(&X[(size_t)gr * 128 + k0])
                          : make_float4(0.f, 0.f, 0.f, 0.f);
      uint lo = f2bf(v.x) | (f2bf(v.y) << 16);
      uint hi = f2bf(v.z) | (f2bf(v.w) << 16);
      int byte = (r * 256 + k0 * 2) ^ ((r & 7) << 4);
      *reinterpret_cast<uint2*>(xt + byte) = make_uint2(lo, hi);
    }
  } else {
    const ushort* X = (const ushort*)Xv;
#pragma unroll
    for (int i = 0; i < 4; ++i) {
      int flat = (i * 256 + t) * 8;
      int r = flat >> 7, k0 = flat & 127;
      int gr = row0 + r;
      uint4 v = (gr < n) ? *reinterpret_cast<const uint4*>(&X[(size_t)gr * 128 + k0])
                         : make_uint4(0u, 0u, 0u, 0u);
      int byte = (r * 256 + k0 * 2) ^ ((r & 7) << 4);
      *reinterpret_cast<uint4*>(xt + byte) = v;
    }
  }
  __syncthreads();

  int wave = t >> 6;
  int lane = t & 63;
  int arow = wave * 16 + (lane & 15);
  int kgrp = (lane >> 4) * 8;

  bf16x8 afrag[4];
#pragma unroll
  for (int ks = 0; ks < 4; ++ks) {
    int kb = ks * 32 + kgrp;
    int byte = (arow * 256 + kb * 2) ^ ((arow & 7) << 4);
    afrag[ks] = *reinterpret_cast<const bf16x8*>(xt + byte);
  }

  f32x4 acc[9];
#pragma unroll
  for (int ct = 0; ct < 9; ++ct) {
    f32x4 a = {0.f, 0.f, 0.f, 0.f};
#pragma unroll
    for (int ks = 0; ks < 4; ++ks) {
      bf16x8 b = *reinterpret_cast<const bf16x8*>(&WF[(size_t)((ct * 4 + ks) * 64 + lane) * 8]);
      a = __builtin_amdgcn_mfma_f32_16x16x32_bf16(afrag[ks], b, a, 0, 0, 0);
    }
    acc[ct] = a;
  }

  int rbase = wave * 16 + (lane >> 4) * 4;
  int csub = lane & 15;
#pragma unroll
  for (int ct = 0; ct < 8; ++ct) {
#pragma unroll
    for (int i = 0; i < 4; ++i) {
      int gr = row0 + rbase + i;
      if (gr < n) XSb[(size_t)gr * 128 + ct * 16 + csub] = (ushort)f2bf(acc[ct][i]);
    }
  }
#pragma unroll
  for (int i = 0; i < 4; ++i) {
    int gr = row0 + rbase + i;
    if (gr < n) AL[(size_t)gr * 16 + csub] = acc[8][i];
  }
}

// ============================ layer 1/2 aggregation: wave-per-node, 8-deep ============================
// MODE 1: write bf16 activations HB. MODE 2: fused lin3 -> XSAL3[n][4] (needs U).
template <int MODE>
__global__ __launch_bounds__(256) void k_gat_agg(const ushort* __restrict__ XSb,
                                                 const float* __restrict__ AL,
                                                 const int* __restrict__ rowptr,
                                                 const int* __restrict__ col,
                                                 const float* __restrict__ bias,
                                                 void* __restrict__ OUTv,
                                                 const float* __restrict__ U, int n) {
  int t = threadIdx.x;
  int lane = t & 63;
  int node = blockIdx.x * 4 + (t >> 6);
  if (node >= n) return;
  int sub = lane & 31;
  int g = lane >> 5;
  int hd = sub >> 2;
  uint xsub = (uint)(sub * 8);  // byte offset in 256B row
  uint hd4 = (uint)(hd * 4);    // byte offset in 64B AL row
  const char* XB = (const char*)XSb;
  const char* AB = (const char*)AL;

  float ald = *(const float*)(AB + (((uint)node << 6) + 32u + hd4));

  // self loop (group 0 only)
  float w0 = __expf(lrelu(*(const float*)(AB + (((uint)node << 6) + hd4)) + ald, LEAKY_ATT));
  if (g != 0) w0 = 0.f;
  uint2 qs = *(const uint2*)(XB + (((uint)node << 8) + xsub));
  float acc0 = w0 * bf_lo(qs.x);
  float acc1 = w0 * bf_hi(qs.x);
  float acc2 = w0 * bf_lo(qs.y);
  float acc3 = w0 * bf_hi(qs.y);
  float den = w0;

  int beg = rowptr[node], end = rowptr[node + 1];
  int base = beg;
  // main: 8 edges per iter (4 per group) — 12 independent loads in flight
  for (; base + 8 <= end; base += 8) {
    int s0 = col[base + g];
    int s1 = col[base + 2 + g];
    int s2 = col[base + 4 + g];
    int s3 = col[base + 6 + g];
    float l0 = *(const float*)(AB + (((uint)s0 << 6) + hd4));
    float l1 = *(const float*)(AB + (((uint)s1 << 6) + hd4));
    float l2 = *(const float*)(AB + (((uint)s2 << 6) + hd4));
    float l3 = *(const float*)(AB + (((uint)s3 << 6) + hd4));
    uint2 q0 = *(const uint2*)(XB + (((uint)s0 << 8) + xsub));
    uint2 q1 = *(const uint2*)(XB + (((uint)s1 << 8) + xsub));
    uint2 q2 = *(const uint2*)(XB + (((uint)s2 << 8) + xsub));
    uint2 q3 = *(const uint2*)(XB + (((uint)s3 << 8) + xsub));
    float wa = __expf(lrelu(l0 + ald, LEAKY_ATT));
    float wb = __expf(lrelu(l1 + ald, LEAKY_ATT));
    float wc = __expf(lrelu(l2 + ald, LEAKY_ATT));
    float wd = __expf(lrelu(l3 + ald, LEAKY_ATT));
    acc0 += wa * bf_lo(q0.x);
    acc1 += wa * bf_hi(q0.x);
    acc2 += wa * bf_lo(q0.y);
    acc3 += wa * bf_hi(q0.y);
    acc0 += wb * bf_lo(q1.x);
    acc1 += wb * bf_hi(q1.x);
    acc2 += wb * bf_lo(q1.y);
    acc3 += wb * bf_hi(q1.y);
    acc0 += wc * bf_lo(q2.x);
    acc1 += wc * bf_hi(q2.x);
    acc2 += wc * bf_lo(q2.y);
    acc3 += wc * bf_hi(q2.y);
    acc0 += wd * bf_lo(q3.x);
    acc1 += wd * bf_hi(q3.x);
    acc2 += wd * bf_lo(q3.y);
    acc3 += wd * bf_hi(q3.y);
    den += (wa + wb) + (wc + wd);
  }
  // 4-edge step
  if (base + 4 <= end) {
    int s0 = col[base + g];
    int s1 = col[base + 2 + g];
    float l0 = *(const float*)(AB + (((uint)s0 << 6) + hd4));
    float l1 = *(const float*)(AB + (((uint)s1 << 6) + hd4));
    uint2 q0 = *(const uint2*)(XB + (((uint)s0 << 8) + xsub));
    uint2 q1 = *(const uint2*)(XB + (((uint)s1 << 8) + xsub));
    float wa = __expf(lrelu(l0 + ald, LEAKY_ATT));
    float wb = __expf(lrelu(l1 + ald, LEAKY_ATT));
    acc0 += wa * bf_lo(q0.x);
    acc1 += wa * bf_hi(q0.x);
    acc2 += wa * bf_lo(q0.y);
    acc3 += wa * bf_hi(q0.y);
    acc0 += wb * bf_lo(q1.x);
    acc1 += wb * bf_hi(q1.x);
    acc2 += wb * bf_lo(q1.y);
    acc3 += wb * bf_hi(q1.y);
    den += wa + wb;
    base += 4;
  }
  // masked remainder (0-3 edges), 2 at a time
  for (; base < end; base += 2) {
    int idx = base + g;
    bool on = idx < end;
    int s = on ? col[idx] : node;
    float l = *(const float*)(AB + (((uint)s << 6) + hd4));
    uint2 q = *(const uint2*)(XB + (((uint)s << 8) + xsub));
    float w = on ? __expf(lrelu(l + ald, LEAKY_ATT)) : 0.f;
    acc0 += w * bf_lo(q.x);
    acc1 += w * bf_hi(q.x);
    acc2 += w * bf_lo(q.y);
    acc3 += w * bf_hi(q.y);
    den += w;
  }

  acc0 += __shfl_xor(acc0, 32);
  acc1 += __shfl_xor(acc1, 32);
  acc2 += __shfl_xor(acc2, 32);
  acc3 += __shfl_xor(acc3, 32);
  den += __shfl_xor(den, 32);

  if (g == 0) {
    int c0 = sub * 4;
    float inv = 1.f / den;
    float4 bv = *reinterpret_cast<const float4*>(&bias[c0]);
    float r0 = lrelu(acc0 * inv + bv.x, LEAKY_ACT);
    float r1 = lrelu(acc1 * inv + bv.y, LEAKY_ACT);
    float r2 = lrelu(acc2 * inv + bv.z, LEAKY_ACT);
    float r3 = lrelu(acc3 * inv + bv.w, LEAKY_ACT);
    if (MODE == 1) {
      ushort* HB = (ushort*)OUTv;
      uint lo = f2bf(r0) | (f2bf(r1) << 16);
      uint hi = f2bf(r2) | (f2bf(r3) << 16);
      *reinterpret_cast<uint2*>(&HB[(size_t)node * 128 + c0]) = make_uint2(lo, hi);
    } else {
      float rr[4] = {r0, r1, r2, r3};
      float p0 = 0.f, p1 = 0.f, p2 = 0.f, p3 = 0.f;
#pragma unroll
      for (int c = 0; c < 4; ++c) {
        float4 uv = *reinterpret_cast<const float4*>(&U[(c0 + c) * 4]);
        p0 += rr[c] * uv.x;
        p1 += rr[c] * uv.y;
        p2 += rr[c] * uv.z;
        p3 += rr[c] * uv.w;
      }
#pragma unroll
      for (int m = 1; m < 32; m <<= 1) {
        p0 += __shfl_xor(p0, m);
        p1 += __shfl_xor(p1, m);
        p2 += __shfl_xor(p2, m);
        p3 += __shfl_xor(p3, m);
      }
      if (sub == 0) {
        float* X3 = (float*)OUTv;
        *reinterpret_cast<float4*>(&X3[(size_t)node * 4]) = make_float4(p0, p1, p2, p3);
      }
    }
  }
}

// ============================ layer 3 aggregation: 4 edges in flight ============================
__global__ __launch_bounds__(256) void k_agg3(const float* __restrict__ XSAL3,
                                              const int* __restrict__ rowptr,
                                              const int* __restrict__ col,
                                              const float* __restrict__ b3,
                                              float* __restrict__ out, int n) {
  int node = blockIdx.x * blockDim.x + threadIdx.x;
  if (node >= n) return;
  const char* XB = (const char*)XSAL3;
  float4 self = *(const float4*)(XB + ((size_t)((uint)node << 4)));
  float ald = self.w;
  float w0 = __expf(lrelu(self.z + ald, LEAKY_ATT));
  float den = w0;
  float a0 = w0 * self.x;
  float a1 = w0 * self.y;
  int jj = rowptr[node], end = rowptr[node + 1];
  for (; jj + 4 <= end; jj += 4) {
    int sA = col[jj], sB = col[jj + 1], sC = col[jj + 2], sD = col[jj + 3];
    float4 vA = *(const float4*)(XB + ((uint)sA << 4));
    float4 vB = *(const float4*)(XB + ((uint)sB << 4));
    float4 vC = *(const float4*)(XB + ((uint)sC << 4));
    float4 vD = *(const float4*)(XB + ((uint)sD << 4));
    float wA = __expf(lrelu(vA.z + ald, LEAKY_ATT));
    float wB = __expf(lrelu(vB.z + ald, LEAKY_ATT));
    float wC = __expf(lrelu(vC.z + ald, LEAKY_ATT));
    float wD = __expf(lrelu(vD.z + ald, LEAKY_ATT));
    a0 += wA * vA.x + wB * vB.x + wC * vC.x + wD * vD.x;
    a1 += wA * vA.y + wB * vB.y + wC * vC.y + wD * vD.y;
    den += (wA + wB) + (wC + wD);
  }
  for (; jj < end; ++jj) {
    int s = col[jj];
    float4 v = *(const float4*)(XB + ((uint)s << 4));
    float w = __expf(lrelu(v.z + ald, LEAKY_ATT));
    den += w;
    a0 += w * v.x;
    a1 += w * v.y;
  }
  out[node * 2 + 0] = a0 / den + b3[0];
  out[node * 2 + 1] = a1 / den + b3[1];
}

// ============================ launch ============================
extern "C" void kernel_launch(void* const* d_in, const int* in_sizes, int n_in,
                              void* d_out, int out_size, void* d_ws, size_t ws_size,
                              hipStream_t stream) {
  const float* x = (const float*)d_in[0];
  const int* ei = (const int*)d_in[1];
  const float* w1s = (const float*)d_in[2];
  const float* w1d = (const float*)d_in[3];
  const float* a1s = (const float*)d_in[4];
  const float* a1d = (const float*)d_in[5];
  const float* b1 = (const float*)d_in[6];
  const float* w2s = (const float*)d_in[7];
  const float* w2d = (const float*)d_in[8];
  const float* a2s = (const float*)d_in[9];
  const float* a2d = (const float*)d_in[10];
  const float* b2 = (const float*)d_in[11];
  const float* w3s = (const float*)d_in[12];
  const float* w3d = (const float*)d_in[13];
  const float* a3s = (const float*)d_in[14];
  const float* a3d = (const float*)d_in[15];
  const float* b3 = (const float*)d_in[16];

  int n = in_sizes[0] / 128;
  int e = in_sizes[1] / 2;
  const int* srcp = ei;
  const int* dstp = ei + e;

  int nb = (n + 255) >> BSHIFT;
  if (nb > 512) return;
  if (n >= (1 << 20)) return;

  size_t off = 0;
  auto alloc = [&](size_t bytes) -> void* {
    void* p = (char*)d_ws + off;
    off += (bytes + 255) & ~(size_t)255;
    return p;
  };
  int* bcnt = (int*)alloc((size_t)nb * 4);
  int* bbase = (int*)alloc((size_t)(nb + 1) * 4);
  int* bcur = (int*)alloc((size_t)nb * 4);
  uint* bpair = (uint*)alloc((size_t)e * 4);
  int* rowptr = (int*)alloc((size_t)(n + 1) * 4);
  int* col = (int*)alloc((size_t)e * 4);
  float* vsd1 = (float*)alloc(128 * 16 * 4);
  float* vsd2 = (float*)alloc(128 * 16 * 4);
  float* u3 = (float*)alloc(128 * 4 * 4);
  ushort* wf1 = (ushort*)alloc(36 * 64 * 8 * 2);
  ushort* wf2 = (ushort*)alloc(36 * 64 * 8 * 2);
  float* al = (float*)alloc((size_t)n * 16 * 4);
  ushort* xsb = (ushort*)alloc((size_t)n * 128 * 2);
  ushort* hb = (ushort*)alloc((size_t)n * 128 * 2);
  float* xsal3 = (float*)alloc((size_t)n * 4 * 4);
  if (off > ws_size) return;

  // CSR build
  hipMemsetAsync(bcnt, 0, (size_t)nb * 4, stream);
  k_bhist<<<512, 256, 0, stream>>>(dstp, e, nb, bcnt);
  k_bscan<<<1, 512, 0, stream>>>(bcnt, nb, bbase, bcur);
  k_bucket<<<(e + CH - 1) / CH, 256, 0, stream>>>(srcp, dstp, e, nb, bcur, bpair);
  k_csr<<<nb, 256, 0, stream>>>(bpair, bbase, n, rowptr, col);

  // weight prep
  k_prep_vsd<<<128, 16, 0, stream>>>(w1s, w1d, a1s, a1d, vsd1);
  k_prep_vsd<<<128, 16, 0, stream>>>(w2s, w2d, a2s, a2d, vsd2);
  k_prep_u3<<<1, 128, 0, stream>>>(w3s, w3d, a3s, a3d, u3);
  k_prep_frag<<<36, 64, 0, stream>>>(w1s, vsd1, wf1);
  k_prep_frag<<<36, 64, 0, stream>>>(w2s, vsd2, wf2);

  int gb = (n + 63) / 64;
  int ab = (n + 3) / 4;
  // layer 1
  k_gemm_mfma<0><<<gb, 256, 0, stream>>>(x, wf1, xsb, al, n);
  k_gat_agg<1><<<ab, 256, 0, stream>>>(xsb, al, rowptr, col, b1, hb, nullptr, n);
  // layer 2 (+fused lin3)
  k_gemm_mfma<1><<<gb, 256, 0, stream>>>(hb, wf2, xsb, al, n);
  k_gat_agg<2><<<ab, 256, 0, stream>>>(xsb, al, rowptr, col, b2, xsal3, u3, n);
  // layer 3
  k_agg3<<<(n + 255) / 256, 256, 0, stream>>>(xsal3, rowptr, col, b3, (float*)d_out, n);
}